// Round 3
// baseline (1222.405 us; speedup 1.0000x reference)
//
#include <hip/hip_runtime.h>
#include <math.h>

// Emulate numpy-fp32 reference: OpenBLAS sgemm fp32 Gram (KC-chunked
// sequential accumulation) -> ssyevd fp32 (ssytd2 + ssteqr + sorm2r,
// LAPACK 3.10+ slartg) -> fp32 MLP. All solver math plain fp32, no FMA
// contraction (matches gfortran -O2 generic x86-64 baseline).
#pragma clang fp contract(off)

#define NACC 55      // 10*11/2 packed lower-triangle entries (i, j<=i)
#define KC_DEFAULT 384  // OpenBLAS SGEMM_DEFAULT_Q (Haswell/Zen)

// ---------------------------------------------------------------------------
// Kernel A: one thread per K-chunk. For each of 55 Gram entries, sequential
// fp32 FMA over the chunk's rows (micro-kernel emulation: one accumulator
// per C element, k ascending). partial[e*prow + c] = chunk partial.
// ---------------------------------------------------------------------------
__global__ __launch_bounds__(256) void gram32_kernel(
    const float* __restrict__ x, float* __restrict__ partial,
    int nrows, int kc, int nchunks, int prow) {
  int c = blockIdx.x * 256 + threadIdx.x;
  if (c >= nchunks) return;
  long k0 = (long)c * kc;
  long rem = (long)nrows - k0;
  int klen = rem < kc ? (int)rem : kc;

  float acc[NACC];
#pragma unroll
  for (int e = 0; e < NACC; ++e) acc[e] = 0.0f;

  const float* row = x + k0 * 10;
  for (int k = 0; k < klen; ++k) {
    const float2* r2 = (const float2*)(row + (long)k * 10);
    float2 t0 = r2[0], t1 = r2[1], t2 = r2[2], t3 = r2[3], t4 = r2[4];
    float a[10];
    a[0] = t0.x; a[1] = t0.y; a[2] = t1.x; a[3] = t1.y; a[4] = t2.x;
    a[5] = t2.y; a[6] = t3.x; a[7] = t3.y; a[8] = t4.x; a[9] = t4.y;
    int e = 0;
#pragma unroll
    for (int i = 0; i < 10; ++i)
#pragma unroll
      for (int j = 0; j <= i; ++j) {
        acc[e] = __builtin_fmaf(a[i], a[j], acc[e]);
        ++e;
      }
  }
#pragma unroll
  for (int e = 0; e < NACC; ++e)
    partial[(long)e * prow + c] = acc[e];
}

// ---------------------------------------------------------------------------
// Kernel B: strictly sequential fp32 fold of chunk partials in K order
// (emulates the driver's per-KC "C += partial" accumulate). Lane e owns
// entry e; its partials are contiguous -> streaming loads.
// ---------------------------------------------------------------------------
__global__ __launch_bounds__(64) void fold32_kernel(
    const float* __restrict__ partial, float* __restrict__ G, int nchunks,
    int prow) {
  int e = threadIdx.x;
  if (e >= NACC || blockIdx.x != 0) return;
  const float* p = partial + (long)e * prow;
  float s = p[0];
  for (int c = 1; c < nchunks; ++c) s = s + p[c];
  G[e] = s;
}

// ---------------------------------------------------------------------------
// Kernel C: ssyevd fp32 replica + fp32 MLP. Single thread.
// ---------------------------------------------------------------------------
__device__ inline float s_sign(float a, float b) {
  return copysignf(fabsf(a), b);  // Fortran SIGN incl. -0.0 semantics
}
__device__ inline float slapy2(float x, float y) {
  float xa = fabsf(x), ya = fabsf(y);
  float w = fmaxf(xa, ya), z = fminf(xa, ya);
  if (z == 0.0f) return w;
  float t = z / w;
  return w * sqrtf(1.0f + t * t);
}
// LAPACK 3.10+ slartg, fast path (magnitudes far from scaling thresholds)
__device__ inline void slartg(float f, float g, float* c, float* s,
                              float* r) {
  if (g == 0.0f) {
    *c = 1.0f; *s = 0.0f; *r = f;
  } else if (f == 0.0f) {
    *c = 0.0f; *s = s_sign(1.0f, g); *r = fabsf(g);
  } else {
    float d = sqrtf(f * f + g * g);
    *c = fabsf(f) / d;
    *r = s_sign(d, f);
    *s = g / (*r);
  }
}
__device__ void slaev2(float a, float b, float c, float* rt1, float* rt2,
                       float* cs1, float* sn1) {
  float sm = a + c, df = a - c;
  float adf = fabsf(df);
  float tb = b + b;
  float ab = fabsf(tb);
  float acmx, acmn;
  if (fabsf(a) > fabsf(c)) { acmx = a; acmn = c; } else { acmx = c; acmn = a; }
  float rt;
  if (adf > ab) { float t = ab / adf; rt = adf * sqrtf(1.0f + t * t); }
  else if (adf < ab) { float t = adf / ab; rt = ab * sqrtf(1.0f + t * t); }
  else rt = ab * sqrtf(2.0f);
  int sgn1;
  if (sm < 0.0f) {
    *rt1 = 0.5f * (sm - rt); sgn1 = -1;
    *rt2 = (acmx / *rt1) * acmn - (b / *rt1) * b;
  } else if (sm > 0.0f) {
    *rt1 = 0.5f * (sm + rt); sgn1 = 1;
    *rt2 = (acmx / *rt1) * acmn - (b / *rt1) * b;
  } else {
    *rt1 = 0.5f * rt; *rt2 = -0.5f * rt; sgn1 = 1;
  }
  int sgn2;
  float cs;
  if (df >= 0.0f) { cs = df + rt; sgn2 = 1; } else { cs = df - rt; sgn2 = -1; }
  float acs = fabsf(cs);
  if (acs > ab) {
    float ct = -tb / cs;
    *sn1 = 1.0f / sqrtf(1.0f + ct * ct);
    *cs1 = ct * (*sn1);
  } else {
    if (ab == 0.0f) { *cs1 = 1.0f; *sn1 = 0.0f; }
    else {
      float tn = -cs / tb;
      *cs1 = 1.0f / sqrtf(1.0f + tn * tn);
      *sn1 = tn * (*cs1);
    }
  }
  if (sgn1 == sgn2) { float tn = *cs1; *cs1 = -(*sn1); *sn1 = tn; }
}

__global__ void solve_kernel(const float* __restrict__ Gp,
                             const float* __restrict__ W1,
                             const float* __restrict__ b1,
                             const float* __restrict__ W2,
                             const float* __restrict__ b2,
                             float* __restrict__ out) {
  __shared__ float A[10][10];
  __shared__ float Z[10][10];
  __shared__ float d[10], e[10], tau[10], wc[10], ws2[10], pv[10];
  if (threadIdx.x != 0 || blockIdx.x != 0) return;
  const int n = 10;

  // unpack lower triangle (numpy eigh UPLO='L' reads lower only; our G is
  // exactly symmetric by construction)
  {
    int k = 0;
    for (int i = 0; i < n; ++i)
      for (int j = 0; j <= i; ++j) { A[i][j] = Gp[k]; A[j][i] = Gp[k]; ++k; }
  }

  // ---- SSYTD2 (UPLO='L') ----
  for (int i = 0; i < n - 1; ++i) {
    float alpha = A[i + 1][i];
    float xn2 = 0.0f;
    for (int k2 = i + 2; k2 < n; ++k2) xn2 = xn2 + A[k2][i] * A[k2][i];
    float xnorm = sqrtf(xn2);
    float taui;
    if (xnorm == 0.0f) {
      taui = 0.0f;
      e[i] = alpha;
    } else {
      float beta = -s_sign(slapy2(alpha, xnorm), alpha);
      taui = (beta - alpha) / beta;
      float sc = 1.0f / (alpha - beta);
      for (int k2 = i + 2; k2 < n; ++k2) A[k2][i] = A[k2][i] * sc;
      A[i + 1][i] = beta;
      e[i] = beta;
    }
    if (taui != 0.0f) {
      A[i + 1][i] = 1.0f;
      for (int r = i + 1; r < n; ++r) {
        float s = 0.0f;
        for (int c2 = i + 1; c2 < n; ++c2) {
          float av = (r >= c2) ? A[r][c2] : A[c2][r];
          s = s + av * A[c2][i];
        }
        pv[r] = taui * s;
      }
      float dot = 0.0f;
      for (int r = i + 1; r < n; ++r) dot = dot + pv[r] * A[r][i];
      float alpha2 = -0.5f * taui * dot;
      for (int r = i + 1; r < n; ++r) pv[r] = pv[r] + alpha2 * A[r][i];
      for (int c2 = i + 1; c2 < n; ++c2)
        for (int r = c2; r < n; ++r)
          A[r][c2] = A[r][c2] - (A[r][i] * pv[c2] + pv[r] * A[c2][i]);
      A[i + 1][i] = e[i];
    }
    d[i] = A[i][i];
    tau[i] = taui;
  }
  d[n - 1] = A[n - 1][n - 1];

  // ---- SSTEQR('I') ----
  for (int i = 0; i < n; ++i)
    for (int j = 0; j < n; ++j) Z[i][j] = (i == j) ? 1.0f : 0.0f;
  const float eps = 5.9604644775390625e-08f;   // SLAMCH('E') = 2^-24
  const float eps2 = 3.5527136788005009e-15f;  // eps^2 = 2^-48
  const float safmin = 1.1754943508222875e-38f;
  const int nmaxit = n * 30;
  int jtot = 0;
  int l1 = 0;

  while (l1 < n) {
    if (l1 > 0) e[l1 - 1] = 0.0f;
    int m = n - 1;
    for (int mm = l1; mm <= n - 2; ++mm) {
      float tst = fabsf(e[mm]);
      if (tst == 0.0f) { m = mm; break; }
      if (tst <= (sqrtf(fabsf(d[mm])) * sqrtf(fabsf(d[mm + 1]))) * eps) {
        e[mm] = 0.0f; m = mm; break;
      }
    }
    int l = l1, lsv = l, lend = m, lendsv = lend;
    l1 = m + 1;
    if (lend == l) continue;
    float anorm = 0.0f;
    for (int k2 = l; k2 <= lend; ++k2) anorm = fmaxf(anorm, fabsf(d[k2]));
    for (int k2 = l; k2 < lend; ++k2) anorm = fmaxf(anorm, fabsf(e[k2]));
    if (anorm == 0.0f) continue;
    if (fabsf(d[lend]) < fabsf(d[l])) { lend = lsv; l = lendsv; }

    if (lend > l) {
      // --- QL ---
      for (;;) {
        int m2 = lend;
        if (l != lend) {
          for (int mm = l; mm <= lend - 1; ++mm) {
            float tst = e[mm] * e[mm];
            if (tst <= (eps2 * fabsf(d[mm])) * fabsf(d[mm + 1]) + safmin) {
              m2 = mm; break;
            }
          }
        }
        if (m2 < lend) e[m2] = 0.0f;
        float p = d[l];
        if (m2 == l) {
          d[l] = p; ++l;
          if (l <= lend) continue;
          break;
        }
        if (m2 == l + 1) {
          float rt1, rt2, cc, ss;
          slaev2(d[l], e[l], d[l + 1], &rt1, &rt2, &cc, &ss);
          for (int i2 = 0; i2 < n; ++i2) {
            float t = Z[i2][l + 1];
            Z[i2][l + 1] = cc * t - ss * Z[i2][l];
            Z[i2][l] = ss * t + cc * Z[i2][l];
          }
          d[l] = rt1; d[l + 1] = rt2; e[l] = 0.0f;
          l += 2;
          if (l <= lend) continue;
          break;
        }
        if (jtot == nmaxit) break;
        ++jtot;
        float g = (d[l + 1] - p) / (2.0f * e[l]);
        float r = slapy2(g, 1.0f);
        g = d[m2] - p + (e[l] / (g + s_sign(r, g)));
        float ss = 1.0f, cc = 1.0f;
        p = 0.0f;
        for (int i2 = m2 - 1; i2 >= l; --i2) {
          float f = ss * e[i2];
          float bb = cc * e[i2];
          slartg(g, f, &cc, &ss, &r);
          if (i2 != m2 - 1) e[i2 + 1] = r;
          g = d[i2 + 1] - p;
          r = (d[i2] - g) * ss + 2.0f * cc * bb;
          p = ss * r;
          d[i2 + 1] = g + p;
          g = cc * r - bb;
          wc[i2] = cc; ws2[i2] = -ss;
        }
        for (int j = m2 - 1; j >= l; --j) {  // SLASR 'R','V','B'
          float cj = wc[j], sj = ws2[j];
          for (int i2 = 0; i2 < n; ++i2) {
            float t = Z[i2][j + 1];
            Z[i2][j + 1] = cj * t - sj * Z[i2][j];
            Z[i2][j] = sj * t + cj * Z[i2][j];
          }
        }
        d[l] = d[l] - p;
        e[l] = g;
      }
    } else {
      // --- QR ---
      for (;;) {
        int m2 = lend;
        if (l != lend) {
          for (int mm = l; mm >= lend + 1; --mm) {
            float tst = e[mm - 1] * e[mm - 1];
            if (tst <= (eps2 * fabsf(d[mm])) * fabsf(d[mm - 1]) + safmin) {
              m2 = mm; break;
            }
          }
        }
        if (m2 > lend) e[m2 - 1] = 0.0f;
        float p = d[l];
        if (m2 == l) {
          d[l] = p; --l;
          if (l >= lend) continue;
          break;
        }
        if (m2 == l - 1) {
          float rt1, rt2, cc, ss;
          slaev2(d[l - 1], e[l - 1], d[l], &rt1, &rt2, &cc, &ss);
          for (int i2 = 0; i2 < n; ++i2) {  // SLASR 'F', cols (l-1, l)
            float t = Z[i2][l];
            Z[i2][l] = cc * t - ss * Z[i2][l - 1];
            Z[i2][l - 1] = ss * t + cc * Z[i2][l - 1];
          }
          d[l - 1] = rt1; d[l] = rt2; e[l - 1] = 0.0f;
          l -= 2;
          if (l >= lend) continue;
          break;
        }
        if (jtot == nmaxit) break;
        ++jtot;
        float g = (d[l - 1] - p) / (2.0f * e[l - 1]);
        float r = slapy2(g, 1.0f);
        g = d[m2] - p + (e[l - 1] / (g + s_sign(r, g)));
        float ss = 1.0f, cc = 1.0f;
        p = 0.0f;
        for (int i2 = m2; i2 <= l - 1; ++i2) {
          float f = ss * e[i2];
          float bb = cc * e[i2];
          slartg(g, f, &cc, &ss, &r);
          if (i2 != m2) e[i2 - 1] = r;
          g = d[i2] - p;
          r = (d[i2 + 1] - g) * ss + 2.0f * cc * bb;
          p = ss * r;
          d[i2] = g + p;
          g = cc * r - bb;
          wc[i2] = cc; ws2[i2] = ss;
        }
        for (int j = m2; j <= l - 1; ++j) {  // SLASR 'R','V','F'
          float cj = wc[j], sj = ws2[j];
          for (int i2 = 0; i2 < n; ++i2) {
            float t = Z[i2][j + 1];
            Z[i2][j + 1] = cj * t - sj * Z[i2][j];
            Z[i2][j] = sj * t + cj * Z[i2][j];
          }
        }
        d[l] = d[l] - p;
        e[l - 1] = g;
      }
    }
  }

  // ascending selection sort
  for (int ii = 1; ii < n; ++ii) {
    int i2 = ii - 1, k2 = i2;
    float p = d[i2];
    for (int j = ii; j < n; ++j)
      if (d[j] < p) { k2 = j; p = d[j]; }
    if (k2 != i2) {
      d[k2] = d[i2]; d[i2] = p;
      for (int r = 0; r < n; ++r) {
        float t = Z[r][i2]; Z[r][i2] = Z[r][k2]; Z[r][k2] = t;
      }
    }
  }

  // ---- apply Householder Q (SORMTR 'L','L','N' -> SORM2R) ----
  for (int i = n - 2; i >= 0; --i) {
    float taui = tau[i];
    if (taui == 0.0f) continue;
    for (int j = 0; j < n; ++j) {
      float w = Z[i + 1][j];
      for (int k2 = i + 2; k2 < n; ++k2) w = w + A[k2][i] * Z[k2][j];
      w = w * taui;
      Z[i + 1][j] = Z[i + 1][j] - w;
      for (int k2 = i + 2; k2 < n; ++k2)
        Z[k2][j] = Z[k2][j] - A[k2][i] * w;
    }
  }

  // ---- fp32 MLP, numpy op order: dot (k ascending) THEN +bias ----
  for (int i = 0; i < n; ++i) {
    float h[16];
    for (int j = 0; j < 16; ++j) {
      float acc = 0.0f;
      for (int k2 = 0; k2 < 10; ++k2) acc = acc + Z[i][k2] * W1[j * 10 + k2];
      acc = acc + b1[j];
      h[j] = fmaxf(acc, 0.0f);
    }
    float o = 0.0f;
    for (int j = 0; j < 16; ++j) o = o + h[j] * W2[j];
    o = o + b2[0];
    float sig = 1.0f / (1.0f + expf(-o));
    out[i] = 0.5f * (sig + 1.0f);
  }
}

// ---------------------------------------------------------------------------
extern "C" void kernel_launch(void* const* d_in, const int* in_sizes, int n_in,
                              void* d_out, int out_size, void* d_ws,
                              size_t ws_size, hipStream_t stream) {
  const float* x  = (const float*)d_in[0];
  const float* W1 = (const float*)d_in[1];
  const float* b1 = (const float*)d_in[2];
  const float* W2 = (const float*)d_in[3];
  const float* b2 = (const float*)d_in[4];
  float* out = (float*)d_out;

  int nrows = in_sizes[0] / 10;  // 4,000,000

  // choose KC; grow if workspace too small (degrades OpenBLAS-matching but
  // stays functional)
  int kc = KC_DEFAULT;
  for (;;) {
    long nchunks = ((long)nrows + kc - 1) / kc;
    long prow = (nchunks + 63) & ~63L;
    size_t need = (size_t)NACC * prow * sizeof(float) + 256;
    if (need <= ws_size || kc > nrows) break;
    kc *= 2;
  }
  int nchunks = (int)(((long)nrows + kc - 1) / kc);
  int prow = (int)(((long)nchunks + 63) & ~63L);

  float* partial = (float*)d_ws;
  float* G = partial + (size_t)NACC * prow;

  int grid = (nchunks + 255) / 256;
  gram32_kernel<<<grid, 256, 0, stream>>>(x, partial, nrows, kc, nchunks,
                                          prow);
  fold32_kernel<<<1, 64, 0, stream>>>(partial, G, nchunks, prow);
  solve_kernel<<<1, 64, 0, stream>>>(G, W1, b1, W2, b2, out);
}

// Round 4
// 266.224 us; speedup vs baseline: 4.5916x; 4.5916x over previous
//
#include <hip/hip_runtime.h>
#include <math.h>

// Bit-exact emulation of the numpy-fp32 reference pipeline:
//   OpenBLAS sgemm fp32 Gram (KC=384 chunked, sequential per-accumulator k
//   order, sequential chunk fold) -> ssyevd fp32 replica -> fp32 MLP.
// Round 3 passed with absmax 0.0 — every fp32 operation ORDER below is
// frozen; this round only changes layout/scheduling for speed.
#pragma clang fp contract(off)

#define NACC 55         // 10*11/2 packed lower-triangle entries (i, j<=i)
#define KC_DEFAULT 384  // OpenBLAS SGEMM_DEFAULT_Q
#define FOLD_LDS 12288  // 48 KB LDS staging capacity (floats)

// ---------------------------------------------------------------------------
// Gram helpers: 4-pair (8-row) group = 20 float4 = 320 B.
// Per-accumulator FMA order is rows ascending — identical to round 3.
// ---------------------------------------------------------------------------
__device__ __forceinline__ void group_load(const float4* __restrict__ xv,
                                           long g, float4* buf) {
#pragma unroll
  for (int t = 0; t < 20; ++t) buf[t] = xv[g * 20 + t];
}

__device__ __forceinline__ void pair_fma_one(const float4 q0, const float4 q1,
                                             const float4 q2, const float4 q3,
                                             const float4 q4, float* acc) {
  float a[10] = {q0.x, q0.y, q0.z, q0.w, q1.x, q1.y, q1.z, q1.w, q2.x, q2.y};
  float b[10] = {q2.z, q2.w, q3.x, q3.y, q3.z, q3.w, q4.x, q4.y, q4.z, q4.w};
  int e = 0;
#pragma unroll
  for (int i = 0; i < 10; ++i)
#pragma unroll
    for (int j = 0; j <= i; ++j) {
      acc[e] = __builtin_fmaf(a[i], a[j], acc[e]);
      acc[e] = __builtin_fmaf(b[i], b[j], acc[e]);
      ++e;
    }
}

__device__ __forceinline__ void group_fma(const float4* buf, float* acc) {
#pragma unroll
  for (int pp = 0; pp < 4; ++pp)
    pair_fma_one(buf[pp * 5 + 0], buf[pp * 5 + 1], buf[pp * 5 + 2],
                 buf[pp * 5 + 3], buf[pp * 5 + 4], acc);
}

// ---------------------------------------------------------------------------
// Kernel A: one thread per K-chunk, 64-thread blocks (163 blocks -> 163 CUs).
// Double-buffered register groups keep ~40 float4 loads in flight over the
// 880-cycle FMA block per group.
// ---------------------------------------------------------------------------
__global__ __launch_bounds__(64, 1) void gram32_kernel(
    const float* __restrict__ x, float* __restrict__ partial,
    int nrows, int kc, int nchunks, int prow) {
  int c = blockIdx.x * 64 + threadIdx.x;
  if (c >= nchunks) return;
  long k0 = (long)c * kc;
  long rem = (long)nrows - k0;
  int klen = rem < kc ? (int)rem : kc;

  float acc[NACC];
#pragma unroll
  for (int e = 0; e < NACC; ++e) acc[e] = 0.0f;

  const float4* __restrict__ xv = (const float4*)(x + k0 * 10);
  int npair = klen >> 1;
  int ngrp = npair >> 2;  // groups of 4 pairs (8 rows)

  float4 bufA[20], bufB[20];

  int g = 0;
  if (ngrp > 0) group_load(xv, 0, bufA);
  while (g < ngrp) {
    if (g + 1 < ngrp) group_load(xv, g + 1, bufB);
    group_fma(bufA, acc);
    ++g;
    if (g >= ngrp) break;
    if (g + 1 < ngrp) group_load(xv, g + 1, bufA);
    group_fma(bufB, acc);
    ++g;
  }
  // leftover pairs
  for (int p = ngrp * 4; p < npair; ++p) {
    float4 v0 = xv[(long)p * 5 + 0];
    float4 v1 = xv[(long)p * 5 + 1];
    float4 v2 = xv[(long)p * 5 + 2];
    float4 v3 = xv[(long)p * 5 + 3];
    float4 v4 = xv[(long)p * 5 + 4];
    pair_fma_one(v0, v1, v2, v3, v4, acc);
  }
  // odd trailing row within the chunk
  if (klen & 1) {
    const float* row = x + (k0 + klen - 1) * 10;
    float a[10];
#pragma unroll
    for (int i = 0; i < 10; ++i) a[i] = row[i];
    int e = 0;
#pragma unroll
    for (int i = 0; i < 10; ++i)
#pragma unroll
      for (int j = 0; j <= i; ++j) {
        acc[e] = __builtin_fmaf(a[i], a[j], acc[e]);
        ++e;
      }
  }
  // entry-major layout: lanes (= consecutive chunks) write coalesced
#pragma unroll
  for (int e = 0; e < NACC; ++e)
    partial[(long)e * prow + c] = acc[e];
}

// ---------------------------------------------------------------------------
// Kernel B: 55 blocks, one Gram entry each. 256 threads stage the entry's
// contiguous partial row into LDS (coalesced float4), then thread 0 runs the
// strictly-sequential fp32 fold (identical order to round 3) from LDS with a
// 16-deep unroll so ds_reads pipeline under the dependent-add chain.
// ---------------------------------------------------------------------------
__global__ __launch_bounds__(256) void fold32_kernel(
    const float* __restrict__ partial, float* __restrict__ G, int nchunks,
    int prow) {
  __shared__ float buf[FOLD_LDS];
  int e = blockIdx.x;
  const float* p = partial + (long)e * prow;

  if (nchunks <= FOLD_LDS) {
    int n4 = nchunks >> 2;
    const float4* p4 = (const float4*)p;
    float4* b4 = (float4*)buf;
    for (int i = threadIdx.x; i < n4; i += 256) b4[i] = p4[i];
    for (int i = (n4 << 2) + threadIdx.x; i < nchunks; i += 256)
      buf[i] = p[i];
    __syncthreads();
    if (threadIdx.x == 0) {
      float s = buf[0];
      int c = 1;
      for (; c + 16 <= nchunks; c += 16) {
        float v[16];
#pragma unroll
        for (int t = 0; t < 16; ++t) v[t] = buf[c + t];
#pragma unroll
        for (int t = 0; t < 16; ++t) s = s + v[t];
      }
      for (; c < nchunks; ++c) s = s + buf[c];
      G[e] = s;
    }
  } else {
    // robustness fallback (not hit for N=4M)
    if (threadIdx.x == 0) {
      float s = p[0];
      for (int c = 1; c < nchunks; ++c) s = s + p[c];
      G[e] = s;
    }
  }
}

// ---------------------------------------------------------------------------
// Kernel C: ssyevd fp32 replica + fp32 MLP. Single thread. (Unchanged from
// round 3 — bit-exact anchor.)
// ---------------------------------------------------------------------------
__device__ inline float s_sign(float a, float b) {
  return copysignf(fabsf(a), b);
}
__device__ inline float slapy2(float x, float y) {
  float xa = fabsf(x), ya = fabsf(y);
  float w = fmaxf(xa, ya), z = fminf(xa, ya);
  if (z == 0.0f) return w;
  float t = z / w;
  return w * sqrtf(1.0f + t * t);
}
__device__ inline void slartg(float f, float g, float* c, float* s,
                              float* r) {
  if (g == 0.0f) {
    *c = 1.0f; *s = 0.0f; *r = f;
  } else if (f == 0.0f) {
    *c = 0.0f; *s = s_sign(1.0f, g); *r = fabsf(g);
  } else {
    float d = sqrtf(f * f + g * g);
    *c = fabsf(f) / d;
    *r = s_sign(d, f);
    *s = g / (*r);
  }
}
__device__ void slaev2(float a, float b, float c, float* rt1, float* rt2,
                       float* cs1, float* sn1) {
  float sm = a + c, df = a - c;
  float adf = fabsf(df);
  float tb = b + b;
  float ab = fabsf(tb);
  float acmx, acmn;
  if (fabsf(a) > fabsf(c)) { acmx = a; acmn = c; } else { acmx = c; acmn = a; }
  float rt;
  if (adf > ab) { float t = ab / adf; rt = adf * sqrtf(1.0f + t * t); }
  else if (adf < ab) { float t = adf / ab; rt = ab * sqrtf(1.0f + t * t); }
  else rt = ab * sqrtf(2.0f);
  int sgn1;
  if (sm < 0.0f) {
    *rt1 = 0.5f * (sm - rt); sgn1 = -1;
    *rt2 = (acmx / *rt1) * acmn - (b / *rt1) * b;
  } else if (sm > 0.0f) {
    *rt1 = 0.5f * (sm + rt); sgn1 = 1;
    *rt2 = (acmx / *rt1) * acmn - (b / *rt1) * b;
  } else {
    *rt1 = 0.5f * rt; *rt2 = -0.5f * rt; sgn1 = 1;
  }
  int sgn2;
  float cs;
  if (df >= 0.0f) { cs = df + rt; sgn2 = 1; } else { cs = df - rt; sgn2 = -1; }
  float acs = fabsf(cs);
  if (acs > ab) {
    float ct = -tb / cs;
    *sn1 = 1.0f / sqrtf(1.0f + ct * ct);
    *cs1 = ct * (*sn1);
  } else {
    if (ab == 0.0f) { *cs1 = 1.0f; *sn1 = 0.0f; }
    else {
      float tn = -cs / tb;
      *cs1 = 1.0f / sqrtf(1.0f + tn * tn);
      *sn1 = tn * (*cs1);
    }
  }
  if (sgn1 == sgn2) { float tn = *cs1; *cs1 = -(*sn1); *sn1 = tn; }
}

__global__ void solve_kernel(const float* __restrict__ Gp,
                             const float* __restrict__ W1,
                             const float* __restrict__ b1,
                             const float* __restrict__ W2,
                             const float* __restrict__ b2,
                             float* __restrict__ out) {
  __shared__ float A[10][10];
  __shared__ float Z[10][10];
  __shared__ float d[10], e[10], tau[10], wc[10], ws2[10], pv[10];
  if (threadIdx.x != 0 || blockIdx.x != 0) return;
  const int n = 10;

  {
    int k = 0;
    for (int i = 0; i < n; ++i)
      for (int j = 0; j <= i; ++j) { A[i][j] = Gp[k]; A[j][i] = Gp[k]; ++k; }
  }

  // ---- SSYTD2 (UPLO='L') ----
  for (int i = 0; i < n - 1; ++i) {
    float alpha = A[i + 1][i];
    float xn2 = 0.0f;
    for (int k2 = i + 2; k2 < n; ++k2) xn2 = xn2 + A[k2][i] * A[k2][i];
    float xnorm = sqrtf(xn2);
    float taui;
    if (xnorm == 0.0f) {
      taui = 0.0f;
      e[i] = alpha;
    } else {
      float beta = -s_sign(slapy2(alpha, xnorm), alpha);
      taui = (beta - alpha) / beta;
      float sc = 1.0f / (alpha - beta);
      for (int k2 = i + 2; k2 < n; ++k2) A[k2][i] = A[k2][i] * sc;
      A[i + 1][i] = beta;
      e[i] = beta;
    }
    if (taui != 0.0f) {
      A[i + 1][i] = 1.0f;
      for (int r = i + 1; r < n; ++r) {
        float s = 0.0f;
        for (int c2 = i + 1; c2 < n; ++c2) {
          float av = (r >= c2) ? A[r][c2] : A[c2][r];
          s = s + av * A[c2][i];
        }
        pv[r] = taui * s;
      }
      float dot = 0.0f;
      for (int r = i + 1; r < n; ++r) dot = dot + pv[r] * A[r][i];
      float alpha2 = -0.5f * taui * dot;
      for (int r = i + 1; r < n; ++r) pv[r] = pv[r] + alpha2 * A[r][i];
      for (int c2 = i + 1; c2 < n; ++c2)
        for (int r = c2; r < n; ++r)
          A[r][c2] = A[r][c2] - (A[r][i] * pv[c2] + pv[r] * A[c2][i]);
      A[i + 1][i] = e[i];
    }
    d[i] = A[i][i];
    tau[i] = taui;
  }
  d[n - 1] = A[n - 1][n - 1];

  // ---- SSTEQR('I') ----
  for (int i = 0; i < n; ++i)
    for (int j = 0; j < n; ++j) Z[i][j] = (i == j) ? 1.0f : 0.0f;
  const float eps = 5.9604644775390625e-08f;
  const float eps2 = 3.5527136788005009e-15f;
  const float safmin = 1.1754943508222875e-38f;
  const int nmaxit = n * 30;
  int jtot = 0;
  int l1 = 0;

  while (l1 < n) {
    if (l1 > 0) e[l1 - 1] = 0.0f;
    int m = n - 1;
    for (int mm = l1; mm <= n - 2; ++mm) {
      float tst = fabsf(e[mm]);
      if (tst == 0.0f) { m = mm; break; }
      if (tst <= (sqrtf(fabsf(d[mm])) * sqrtf(fabsf(d[mm + 1]))) * eps) {
        e[mm] = 0.0f; m = mm; break;
      }
    }
    int l = l1, lsv = l, lend = m, lendsv = lend;
    l1 = m + 1;
    if (lend == l) continue;
    float anorm = 0.0f;
    for (int k2 = l; k2 <= lend; ++k2) anorm = fmaxf(anorm, fabsf(d[k2]));
    for (int k2 = l; k2 < lend; ++k2) anorm = fmaxf(anorm, fabsf(e[k2]));
    if (anorm == 0.0f) continue;
    if (fabsf(d[lend]) < fabsf(d[l])) { lend = lsv; l = lendsv; }

    if (lend > l) {
      // --- QL ---
      for (;;) {
        int m2 = lend;
        if (l != lend) {
          for (int mm = l; mm <= lend - 1; ++mm) {
            float tst = e[mm] * e[mm];
            if (tst <= (eps2 * fabsf(d[mm])) * fabsf(d[mm + 1]) + safmin) {
              m2 = mm; break;
            }
          }
        }
        if (m2 < lend) e[m2] = 0.0f;
        float p = d[l];
        if (m2 == l) {
          d[l] = p; ++l;
          if (l <= lend) continue;
          break;
        }
        if (m2 == l + 1) {
          float rt1, rt2, cc, ss;
          slaev2(d[l], e[l], d[l + 1], &rt1, &rt2, &cc, &ss);
          for (int i2 = 0; i2 < n; ++i2) {
            float t = Z[i2][l + 1];
            Z[i2][l + 1] = cc * t - ss * Z[i2][l];
            Z[i2][l] = ss * t + cc * Z[i2][l];
          }
          d[l] = rt1; d[l + 1] = rt2; e[l] = 0.0f;
          l += 2;
          if (l <= lend) continue;
          break;
        }
        if (jtot == nmaxit) break;
        ++jtot;
        float g = (d[l + 1] - p) / (2.0f * e[l]);
        float r = slapy2(g, 1.0f);
        g = d[m2] - p + (e[l] / (g + s_sign(r, g)));
        float ss = 1.0f, cc = 1.0f;
        p = 0.0f;
        for (int i2 = m2 - 1; i2 >= l; --i2) {
          float f = ss * e[i2];
          float bb = cc * e[i2];
          slartg(g, f, &cc, &ss, &r);
          if (i2 != m2 - 1) e[i2 + 1] = r;
          g = d[i2 + 1] - p;
          r = (d[i2] - g) * ss + 2.0f * cc * bb;
          p = ss * r;
          d[i2 + 1] = g + p;
          g = cc * r - bb;
          wc[i2] = cc; ws2[i2] = -ss;
        }
        for (int j = m2 - 1; j >= l; --j) {  // SLASR 'R','V','B'
          float cj = wc[j], sj = ws2[j];
          for (int i2 = 0; i2 < n; ++i2) {
            float t = Z[i2][j + 1];
            Z[i2][j + 1] = cj * t - sj * Z[i2][j];
            Z[i2][j] = sj * t + cj * Z[i2][j];
          }
        }
        d[l] = d[l] - p;
        e[l] = g;
      }
    } else {
      // --- QR ---
      for (;;) {
        int m2 = lend;
        if (l != lend) {
          for (int mm = l; mm >= lend + 1; --mm) {
            float tst = e[mm - 1] * e[mm - 1];
            if (tst <= (eps2 * fabsf(d[mm])) * fabsf(d[mm - 1]) + safmin) {
              m2 = mm; break;
            }
          }
        }
        if (m2 > lend) e[m2 - 1] = 0.0f;
        float p = d[l];
        if (m2 == l) {
          d[l] = p; --l;
          if (l >= lend) continue;
          break;
        }
        if (m2 == l - 1) {
          float rt1, rt2, cc, ss;
          slaev2(d[l - 1], e[l - 1], d[l], &rt1, &rt2, &cc, &ss);
          for (int i2 = 0; i2 < n; ++i2) {
            float t = Z[i2][l];
            Z[i2][l] = cc * t - ss * Z[i2][l - 1];
            Z[i2][l - 1] = ss * t + cc * Z[i2][l - 1];
          }
          d[l - 1] = rt1; d[l] = rt2; e[l - 1] = 0.0f;
          l -= 2;
          if (l >= lend) continue;
          break;
        }
        if (jtot == nmaxit) break;
        ++jtot;
        float g = (d[l - 1] - p) / (2.0f * e[l - 1]);
        float r = slapy2(g, 1.0f);
        g = d[m2] - p + (e[l - 1] / (g + s_sign(r, g)));
        float ss = 1.0f, cc = 1.0f;
        p = 0.0f;
        for (int i2 = m2; i2 <= l - 1; ++i2) {
          float f = ss * e[i2];
          float bb = cc * e[i2];
          slartg(g, f, &cc, &ss, &r);
          if (i2 != m2) e[i2 - 1] = r;
          g = d[i2] - p;
          r = (d[i2 + 1] - g) * ss + 2.0f * cc * bb;
          p = ss * r;
          d[i2] = g + p;
          g = cc * r - bb;
          wc[i2] = cc; ws2[i2] = ss;
        }
        for (int j = m2; j <= l - 1; ++j) {  // SLASR 'R','V','F'
          float cj = wc[j], sj = ws2[j];
          for (int i2 = 0; i2 < n; ++i2) {
            float t = Z[i2][j + 1];
            Z[i2][j + 1] = cj * t - sj * Z[i2][j];
            Z[i2][j] = sj * t + cj * Z[i2][j];
          }
        }
        d[l] = d[l] - p;
        e[l - 1] = g;
      }
    }
  }

  // ascending selection sort
  for (int ii = 1; ii < n; ++ii) {
    int i2 = ii - 1, k2 = i2;
    float p = d[i2];
    for (int j = ii; j < n; ++j)
      if (d[j] < p) { k2 = j; p = d[j]; }
    if (k2 != i2) {
      d[k2] = d[i2]; d[i2] = p;
      for (int r = 0; r < n; ++r) {
        float t = Z[r][i2]; Z[r][i2] = Z[r][k2]; Z[r][k2] = t;
      }
    }
  }

  // ---- SORM2R (apply Householder Q) ----
  for (int i = n - 2; i >= 0; --i) {
    float taui = tau[i];
    if (taui == 0.0f) continue;
    for (int j = 0; j < n; ++j) {
      float w = Z[i + 1][j];
      for (int k2 = i + 2; k2 < n; ++k2) w = w + A[k2][i] * Z[k2][j];
      w = w * taui;
      Z[i + 1][j] = Z[i + 1][j] - w;
      for (int k2 = i + 2; k2 < n; ++k2)
        Z[k2][j] = Z[k2][j] - A[k2][i] * w;
    }
  }

  // ---- fp32 MLP, numpy op order ----
  for (int i = 0; i < n; ++i) {
    float h[16];
    for (int j = 0; j < 16; ++j) {
      float acc = 0.0f;
      for (int k2 = 0; k2 < 10; ++k2) acc = acc + Z[i][k2] * W1[j * 10 + k2];
      acc = acc + b1[j];
      h[j] = fmaxf(acc, 0.0f);
    }
    float o = 0.0f;
    for (int j = 0; j < 16; ++j) o = o + h[j] * W2[j];
    o = o + b2[0];
    float sig = 1.0f / (1.0f + expf(-o));
    out[i] = 0.5f * (sig + 1.0f);
  }
}

// ---------------------------------------------------------------------------
extern "C" void kernel_launch(void* const* d_in, const int* in_sizes, int n_in,
                              void* d_out, int out_size, void* d_ws,
                              size_t ws_size, hipStream_t stream) {
  const float* x  = (const float*)d_in[0];
  const float* W1 = (const float*)d_in[1];
  const float* b1 = (const float*)d_in[2];
  const float* W2 = (const float*)d_in[3];
  const float* b2 = (const float*)d_in[4];
  float* out = (float*)d_out;

  int nrows = in_sizes[0] / 10;  // 4,000,000

  int kc = KC_DEFAULT;
  for (;;) {
    long nchunks = ((long)nrows + kc - 1) / kc;
    long prow = (nchunks + 63) & ~63L;
    size_t need = (size_t)NACC * prow * sizeof(float) + 256;
    if (need <= ws_size || kc > nrows) break;
    kc *= 2;
  }
  int nchunks = (int)(((long)nrows + kc - 1) / kc);
  int prow = (int)(((long)nchunks + 63) & ~63L);

  float* partial = (float*)d_ws;
  float* G = partial + (size_t)NACC * prow;

  int grid = (nchunks + 63) / 64;
  gram32_kernel<<<grid, 64, 0, stream>>>(x, partial, nrows, kc, nchunks,
                                         prow);
  fold32_kernel<<<NACC, 256, 0, stream>>>(partial, G, nchunks, prow);
  solve_kernel<<<1, 64, 0, stream>>>(G, W1, b1, W2, b2, out);
}

// Round 5
// 200.997 us; speedup vs baseline: 6.0817x; 1.3245x over previous
//
#include <hip/hip_runtime.h>
#include <math.h>

// Bit-exact emulation of the numpy-fp32 reference pipeline:
//   OpenBLAS sgemm fp32 Gram (KC=384 chunked, sequential per-accumulator k
//   order, sequential chunk fold) -> ssyevd fp32 replica -> fp32 MLP.
// Rounds 3/4 passed with absmax 0.0 — every fp32 operation ORDER below is
// frozen. This round: solver storage moves from single-lane LDS to
// lane-parallel registers (same ops, same order, bit-exact).
#pragma clang fp contract(off)

#define NACC 55         // 10*11/2 packed lower-triangle entries (i, j<=i)
#define KC_DEFAULT 384  // OpenBLAS SGEMM_DEFAULT_Q
#define FOLD_LDS 12288  // 48 KB LDS staging capacity (floats)

// ---------------------------------------------------------------------------
// Gram helpers: 4-pair (8-row) group = 20 float4 = 320 B.
// ---------------------------------------------------------------------------
__device__ __forceinline__ void group_load(const float4* __restrict__ xv,
                                           long g, float4* buf) {
#pragma unroll
  for (int t = 0; t < 20; ++t) buf[t] = xv[g * 20 + t];
}

__device__ __forceinline__ void pair_fma_one(const float4 q0, const float4 q1,
                                             const float4 q2, const float4 q3,
                                             const float4 q4, float* acc) {
  float a[10] = {q0.x, q0.y, q0.z, q0.w, q1.x, q1.y, q1.z, q1.w, q2.x, q2.y};
  float b[10] = {q2.z, q2.w, q3.x, q3.y, q3.z, q3.w, q4.x, q4.y, q4.z, q4.w};
  int e = 0;
#pragma unroll
  for (int i = 0; i < 10; ++i)
#pragma unroll
    for (int j = 0; j <= i; ++j) {
      acc[e] = __builtin_fmaf(a[i], a[j], acc[e]);
      acc[e] = __builtin_fmaf(b[i], b[j], acc[e]);
      ++e;
    }
}

__device__ __forceinline__ void group_fma(const float4* buf, float* acc) {
#pragma unroll
  for (int pp = 0; pp < 4; ++pp)
    pair_fma_one(buf[pp * 5 + 0], buf[pp * 5 + 1], buf[pp * 5 + 2],
                 buf[pp * 5 + 3], buf[pp * 5 + 4], acc);
}

// ---------------------------------------------------------------------------
// Kernel A: one thread per K-chunk (unchanged from round 4).
// ---------------------------------------------------------------------------
__global__ __launch_bounds__(64, 1) void gram32_kernel(
    const float* __restrict__ x, float* __restrict__ partial,
    int nrows, int kc, int nchunks, int prow) {
  int c = blockIdx.x * 64 + threadIdx.x;
  if (c >= nchunks) return;
  long k0 = (long)c * kc;
  long rem = (long)nrows - k0;
  int klen = rem < kc ? (int)rem : kc;

  float acc[NACC];
#pragma unroll
  for (int e = 0; e < NACC; ++e) acc[e] = 0.0f;

  const float4* __restrict__ xv = (const float4*)(x + k0 * 10);
  int npair = klen >> 1;
  int ngrp = npair >> 2;

  float4 bufA[20], bufB[20];

  int g = 0;
  if (ngrp > 0) group_load(xv, 0, bufA);
  while (g < ngrp) {
    if (g + 1 < ngrp) group_load(xv, g + 1, bufB);
    group_fma(bufA, acc);
    ++g;
    if (g >= ngrp) break;
    if (g + 1 < ngrp) group_load(xv, g + 1, bufA);
    group_fma(bufB, acc);
    ++g;
  }
  for (int p = ngrp * 4; p < npair; ++p) {
    float4 v0 = xv[(long)p * 5 + 0];
    float4 v1 = xv[(long)p * 5 + 1];
    float4 v2 = xv[(long)p * 5 + 2];
    float4 v3 = xv[(long)p * 5 + 3];
    float4 v4 = xv[(long)p * 5 + 4];
    pair_fma_one(v0, v1, v2, v3, v4, acc);
  }
  if (klen & 1) {
    const float* row = x + (k0 + klen - 1) * 10;
    float a[10];
#pragma unroll
    for (int i = 0; i < 10; ++i) a[i] = row[i];
    int e = 0;
#pragma unroll
    for (int i = 0; i < 10; ++i)
#pragma unroll
      for (int j = 0; j <= i; ++j) {
        acc[e] = __builtin_fmaf(a[i], a[j], acc[e]);
        ++e;
      }
  }
#pragma unroll
  for (int e = 0; e < NACC; ++e)
    partial[(long)e * prow + c] = acc[e];
}

// ---------------------------------------------------------------------------
// Kernel B: 55 blocks, one Gram entry each (unchanged from round 4).
// ---------------------------------------------------------------------------
__global__ __launch_bounds__(256) void fold32_kernel(
    const float* __restrict__ partial, float* __restrict__ G, int nchunks,
    int prow) {
  __shared__ float buf[FOLD_LDS];
  int e = blockIdx.x;
  const float* p = partial + (long)e * prow;

  if (nchunks <= FOLD_LDS) {
    int n4 = nchunks >> 2;
    const float4* p4 = (const float4*)p;
    float4* b4 = (float4*)buf;
    for (int i = threadIdx.x; i < n4; i += 256) b4[i] = p4[i];
    for (int i = (n4 << 2) + threadIdx.x; i < nchunks; i += 256)
      buf[i] = p[i];
    __syncthreads();
    if (threadIdx.x == 0) {
      float s = buf[0];
      int c = 1;
      for (; c + 16 <= nchunks; c += 16) {
        float v[16];
#pragma unroll
        for (int t = 0; t < 16; ++t) v[t] = buf[c + t];
#pragma unroll
        for (int t = 0; t < 16; ++t) s = s + v[t];
      }
      for (; c < nchunks; ++c) s = s + buf[c];
      G[e] = s;
    }
  } else {
    if (threadIdx.x == 0) {
      float s = p[0];
      for (int c = 1; c < nchunks; ++c) s = s + p[c];
      G[e] = s;
    }
  }
}

// ---------------------------------------------------------------------------
// Kernel C: ssyevd fp32 replica + fp32 MLP — register-resident, one wave.
// d/e/tau/wc/ws: redundant per-lane register arrays (static indexing only;
// runtime singles via cndmask extract/insert). A: row-per-lane. Z: column-
// per-lane. Cross-lane via __shfl. All fp ops identical order to round 4.
// ---------------------------------------------------------------------------
__device__ __forceinline__ float s_sign(float a, float b) {
  return copysignf(fabsf(a), b);
}
__device__ __forceinline__ float slapy2(float x, float y) {
  float xa = fabsf(x), ya = fabsf(y);
  float w = fmaxf(xa, ya), z = fminf(xa, ya);
  if (z == 0.0f) return w;
  float t = z / w;
  return w * sqrtf(1.0f + t * t);
}
__device__ __forceinline__ void slartg(float f, float g, float* c, float* s,
                                       float* r) {
  if (g == 0.0f) {
    *c = 1.0f; *s = 0.0f; *r = f;
  } else if (f == 0.0f) {
    *c = 0.0f; *s = s_sign(1.0f, g); *r = fabsf(g);
  } else {
    float d = sqrtf(f * f + g * g);
    *c = fabsf(f) / d;
    *r = s_sign(d, f);
    *s = g / (*r);
  }
}
__device__ void slaev2(float a, float b, float c, float* rt1, float* rt2,
                       float* cs1, float* sn1) {
  float sm = a + c, df = a - c;
  float adf = fabsf(df);
  float tb = b + b;
  float ab = fabsf(tb);
  float acmx, acmn;
  if (fabsf(a) > fabsf(c)) { acmx = a; acmn = c; } else { acmx = c; acmn = a; }
  float rt;
  if (adf > ab) { float t = ab / adf; rt = adf * sqrtf(1.0f + t * t); }
  else if (adf < ab) { float t = adf / ab; rt = ab * sqrtf(1.0f + t * t); }
  else rt = ab * sqrtf(2.0f);
  int sgn1;
  if (sm < 0.0f) {
    *rt1 = 0.5f * (sm - rt); sgn1 = -1;
    *rt2 = (acmx / *rt1) * acmn - (b / *rt1) * b;
  } else if (sm > 0.0f) {
    *rt1 = 0.5f * (sm + rt); sgn1 = 1;
    *rt2 = (acmx / *rt1) * acmn - (b / *rt1) * b;
  } else {
    *rt1 = 0.5f * rt; *rt2 = -0.5f * rt; sgn1 = 1;
  }
  int sgn2;
  float cs;
  if (df >= 0.0f) { cs = df + rt; sgn2 = 1; } else { cs = df - rt; sgn2 = -1; }
  float acs = fabsf(cs);
  if (acs > ab) {
    float ct = -tb / cs;
    *sn1 = 1.0f / sqrtf(1.0f + ct * ct);
    *cs1 = ct * (*sn1);
  } else {
    if (ab == 0.0f) { *cs1 = 1.0f; *sn1 = 0.0f; }
    else {
      float tn = -cs / tb;
      *cs1 = 1.0f / sqrtf(1.0f + tn * tn);
      *sn1 = tn * (*cs1);
    }
  }
  if (sgn1 == sgn2) { float tn = *cs1; *cs1 = -(*sn1); *sn1 = tn; }
}

// runtime-index access into a statically-indexed register array (10 deep)
__device__ __forceinline__ float xget(const float* a, int idx) {
  float r = a[0];
#pragma unroll
  for (int k = 1; k < 10; ++k)
    if (idx == k) r = a[k];
  return r;
}
__device__ __forceinline__ void xput(float* a, int idx, float v) {
#pragma unroll
  for (int k = 0; k < 10; ++k)
    if (idx == k) a[k] = v;
}

__global__ __launch_bounds__(64) void solve_kernel(
    const float* __restrict__ Gp, const float* __restrict__ W1,
    const float* __restrict__ b1, const float* __restrict__ W2,
    const float* __restrict__ b2, float* __restrict__ out) {
  const int lane = threadIdx.x;
  const int myrow = lane < 10 ? lane : 9;

  // A: lane r holds logical symmetric row r (invariant maintained; mul/add
  // commutativity makes mirrored updates bit-identical to lower-triangle ops)
  float row[10];
#pragma unroll
  for (int c = 0; c < 10; ++c) {
    int rr = myrow >= c ? myrow : c;
    int cc = myrow >= c ? c : myrow;
    row[c] = Gp[rr * (rr + 1) / 2 + cc];
  }

  float d[10], e[10], tau[9];

  // ---- SSYTD2 (UPLO='L') ----
#pragma unroll
  for (int i = 0; i < 9; ++i) {
    float v[10];
    {
      float myci = row[i];
#pragma unroll
      for (int k = 0; k < 10; ++k) v[k] = __shfl(myci, k, 64);
    }
    float alpha = v[i + 1];
    float xn2 = 0.0f;
#pragma unroll
    for (int k = i + 2; k < 10; ++k) xn2 = xn2 + v[k] * v[k];
    float xnorm = sqrtf(xn2);
    float taui;
    if (xnorm == 0.0f) {
      taui = 0.0f;
      e[i] = alpha;
    } else {
      float beta = -s_sign(slapy2(alpha, xnorm), alpha);
      taui = (beta - alpha) / beta;
      float sc = 1.0f / (alpha - beta);
#pragma unroll
      for (int k = i + 2; k < 10; ++k) v[k] = v[k] * sc;
      if (lane >= i + 2 && lane < 10) row[i] = row[i] * sc;
      if (lane == i) {
#pragma unroll
        for (int c = i + 2; c < 10; ++c) row[c] = row[c] * sc;
      }
      if (lane == i + 1) row[i] = beta;
      if (lane == i) row[i + 1] = beta;
      e[i] = beta;
    }
    if (taui != 0.0f) {
      v[i + 1] = 1.0f;
      float vme = (lane == i + 1)
                      ? 1.0f
                      : ((lane >= i + 2 && lane < 10) ? row[i] : 0.0f);
      // pv[r] = taui * sum_{c2=i+1..9} M[r][c2]*v[c2]  (sequential in c2)
      float s = 0.0f;
#pragma unroll
      for (int c2 = i + 1; c2 < 10; ++c2) s = s + row[c2] * v[c2];
      float pvr = taui * s;
      float pva[10];
#pragma unroll
      for (int k = 0; k < 10; ++k) pva[k] = __shfl(pvr, k, 64);
      float dot = 0.0f;
#pragma unroll
      for (int k = i + 1; k < 10; ++k) dot = dot + pva[k] * v[k];
      float alpha2 = -0.5f * taui * dot;
      pvr = pvr + alpha2 * vme;
#pragma unroll
      for (int k = 0; k < 10; ++k) pva[k] = pva[k] + alpha2 * v[k];
      // symmetric rank-2 update (rows/cols i+1..9)
      if (lane >= i + 1 && lane < 10) {
#pragma unroll
        for (int c2 = i + 1; c2 < 10; ++c2)
          row[c2] = row[c2] - (vme * pva[c2] + pvr * v[c2]);
      }
    }
    tau[i] = taui;
    d[i] = __shfl(row[i], i, 64);
  }
  d[9] = __shfl(row[9], 9, 64);

  // ---- SSTEQR('I') ---- Z: lane c owns column c
  float z[10];
#pragma unroll
  for (int rr2 = 0; rr2 < 10; ++rr2) z[rr2] = (lane == rr2) ? 1.0f : 0.0f;

  const float eps = 5.9604644775390625e-08f;
  const float eps2 = 3.5527136788005009e-15f;
  const float safmin = 1.1754943508222875e-38f;
  const int nmaxit = 300;
  int jtot = 0;
  int l1 = 0;

  while (l1 < 10) {
    if (l1 > 0) xput(e, l1 - 1, 0.0f);
    int m = 9;
    {
      bool fnd = false;
#pragma unroll
      for (int mm = 0; mm < 9; ++mm) {
        if (!fnd && mm >= l1) {
          float tst = fabsf(e[mm]);
          if (tst == 0.0f) {
            m = mm; fnd = true;
          } else if (tst <=
                     (sqrtf(fabsf(d[mm])) * sqrtf(fabsf(d[mm + 1]))) * eps) {
            e[mm] = 0.0f; m = mm; fnd = true;
          }
        }
      }
    }
    int l = l1, lsv = l, lend = m, lendsv = lend;
    l1 = m + 1;
    if (lend == l) continue;
    float anorm = 0.0f;
#pragma unroll
    for (int k = 0; k < 10; ++k)
      if (k >= l && k <= lend) anorm = fmaxf(anorm, fabsf(d[k]));
#pragma unroll
    for (int k = 0; k < 9; ++k)
      if (k >= l && k < lend) anorm = fmaxf(anorm, fabsf(e[k]));
    if (anorm == 0.0f) continue;
    if (fabsf(xget(d, lend)) < fabsf(xget(d, l))) { lend = lsv; l = lendsv; }

    if (lend > l) {
      // --- QL ---
      for (;;) {
        int m2 = lend;
        if (l != lend) {
          bool fnd = false;
#pragma unroll
          for (int mm = 0; mm < 9; ++mm) {
            if (!fnd && mm >= l && mm <= lend - 1) {
              float tst = e[mm] * e[mm];
              if (tst <= (eps2 * fabsf(d[mm])) * fabsf(d[mm + 1]) + safmin) {
                m2 = mm; fnd = true;
              }
            }
          }
        }
        if (m2 < lend) xput(e, m2, 0.0f);
        float p = xget(d, l);
        if (m2 == l) {
          ++l;
          if (l <= lend) continue;
          break;
        }
        if (m2 == l + 1) {
          float rt1, rt2, cc2, ss2;
          slaev2(xget(d, l), xget(e, l), xget(d, l + 1), &rt1, &rt2, &cc2,
                 &ss2);
#pragma unroll
          for (int rr2 = 0; rr2 < 10; ++rr2) {
            float zl = __shfl(z[rr2], l, 64);
            float zl1 = __shfl(z[rr2], l + 1, 64);
            float t = zl1;
            float nj1 = cc2 * t - ss2 * zl;
            float nj = ss2 * t + cc2 * zl;
            if (lane == l) z[rr2] = nj;
            if (lane == l + 1) z[rr2] = nj1;
          }
          xput(d, l, rt1);
          xput(d, l + 1, rt2);
          xput(e, l, 0.0f);
          l += 2;
          if (l <= lend) continue;
          break;
        }
        if (jtot == nmaxit) break;
        ++jtot;
        float g = (xget(d, l + 1) - p) / (2.0f * xget(e, l));
        float r2 = slapy2(g, 1.0f);
        g = xget(d, m2) - p + (xget(e, l) / (g + s_sign(r2, g)));
        float ss = 1.0f, cc = 1.0f;
        p = 0.0f;
        float wcA[10], wsA[10];
#pragma unroll
        for (int i2 = 8; i2 >= 0; --i2) {
          if (i2 >= l && i2 <= m2 - 1) {
            float f = ss * e[i2];
            float bb = cc * e[i2];
            slartg(g, f, &cc, &ss, &r2);
            if (i2 != m2 - 1) e[i2 + 1] = r2;
            g = d[i2 + 1] - p;
            r2 = (d[i2] - g) * ss + 2.0f * cc * bb;
            p = ss * r2;
            d[i2 + 1] = g + p;
            g = cc * r2 - bb;
            wcA[i2] = cc;
            wsA[i2] = -ss;
          }
        }
#pragma unroll
        for (int j = 8; j >= 0; --j) {  // SLASR 'R','V','B'
          if (j >= l && j <= m2 - 1) {
            float cj = wcA[j], sj = wsA[j];
#pragma unroll
            for (int rr2 = 0; rr2 < 10; ++rr2) {
              float zj = __shfl(z[rr2], j, 64);
              float zj1 = __shfl(z[rr2], j + 1, 64);
              float t = zj1;
              float nj1 = cj * t - sj * zj;
              float nj = sj * t + cj * zj;
              if (lane == j) z[rr2] = nj;
              if (lane == j + 1) z[rr2] = nj1;
            }
          }
        }
        xput(d, l, xget(d, l) - p);
        xput(e, l, g);
      }
    } else {
      // --- QR ---
      for (;;) {
        int m2 = lend;
        if (l != lend) {
          bool fnd = false;
#pragma unroll
          for (int mm = 9; mm >= 1; --mm) {
            if (!fnd && mm <= l && mm >= lend + 1) {
              float tst = e[mm - 1] * e[mm - 1];
              if (tst <= (eps2 * fabsf(d[mm])) * fabsf(d[mm - 1]) + safmin) {
                m2 = mm; fnd = true;
              }
            }
          }
        }
        if (m2 > lend) xput(e, m2 - 1, 0.0f);
        float p = xget(d, l);
        if (m2 == l) {
          --l;
          if (l >= lend) continue;
          break;
        }
        if (m2 == l - 1) {
          float rt1, rt2, cc2, ss2;
          slaev2(xget(d, l - 1), xget(e, l - 1), xget(d, l), &rt1, &rt2, &cc2,
                 &ss2);
#pragma unroll
          for (int rr2 = 0; rr2 < 10; ++rr2) {
            float zl = __shfl(z[rr2], l, 64);
            float zlm = __shfl(z[rr2], l - 1, 64);
            float t = zl;
            float nl = cc2 * t - ss2 * zlm;
            float nlm = ss2 * t + cc2 * zlm;
            if (lane == l) z[rr2] = nl;
            if (lane == l - 1) z[rr2] = nlm;
          }
          xput(d, l - 1, rt1);
          xput(d, l, rt2);
          xput(e, l - 1, 0.0f);
          l -= 2;
          if (l >= lend) continue;
          break;
        }
        if (jtot == nmaxit) break;
        ++jtot;
        float g = (xget(d, l - 1) - p) / (2.0f * xget(e, l - 1));
        float r2 = slapy2(g, 1.0f);
        g = xget(d, m2) - p + (xget(e, l - 1) / (g + s_sign(r2, g)));
        float ss = 1.0f, cc = 1.0f;
        p = 0.0f;
        float wcA[10], wsA[10];
#pragma unroll
        for (int i2 = 0; i2 <= 8; ++i2) {
          if (i2 >= m2 && i2 <= l - 1) {
            float f = ss * e[i2];
            float bb = cc * e[i2];
            slartg(g, f, &cc, &ss, &r2);
            if (i2 != m2) e[(i2 > 0) ? i2 - 1 : 0] = r2;  // i2==0 => no write
            g = d[i2] - p;
            r2 = (d[i2 + 1] - g) * ss + 2.0f * cc * bb;
            p = ss * r2;
            d[i2] = g + p;
            g = cc * r2 - bb;
            wcA[i2] = cc;
            wsA[i2] = ss;
          }
        }
#pragma unroll
        for (int j = 0; j <= 8; ++j) {  // SLASR 'R','V','F'
          if (j >= m2 && j <= l - 1) {
            float cj = wcA[j], sj = wsA[j];
#pragma unroll
            for (int rr2 = 0; rr2 < 10; ++rr2) {
              float zj = __shfl(z[rr2], j, 64);
              float zj1 = __shfl(z[rr2], j + 1, 64);
              float t = zj1;
              float nj1 = cj * t - sj * zj;
              float nj = sj * t + cj * zj;
              if (lane == j) z[rr2] = nj;
              if (lane == j + 1) z[rr2] = nj1;
            }
          }
        }
        xput(d, l, xget(d, l) - p);
        xput(e, l - 1, g);  // l>=2 here; xput ignores idx<0 anyway
      }
    }
  }

  // ---- ascending selection sort ----
#pragma unroll
  for (int ii = 1; ii < 10; ++ii) {
    const int i2 = ii - 1;
    int k2 = i2;
    float pmin = d[i2];
#pragma unroll
    for (int j = ii; j < 10; ++j)
      if (d[j] < pmin) { k2 = j; pmin = d[j]; }
    if (k2 != i2) {
      xput(d, k2, d[i2]);
      d[i2] = pmin;
#pragma unroll
      for (int rr2 = 0; rr2 < 10; ++rr2) {
        float zi = __shfl(z[rr2], i2, 64);
        float zk = __shfl(z[rr2], k2, 64);
        if (lane == i2) z[rr2] = zk;
        if (lane == k2) z[rr2] = zi;
      }
    }
  }

  // ---- SORM2R: V = H(0)...H(7) * Z ; lane j owns column j ----
#pragma unroll
  for (int i = 8; i >= 0; --i) {
    float taui = tau[i];
    if (taui != 0.0f) {
      float hv[10];
      {
        float myci = row[i];
#pragma unroll
        for (int k = 0; k < 10; ++k) hv[k] = __shfl(myci, k, 64);
      }
      float w = z[i + 1];
#pragma unroll
      for (int k2 = i + 2; k2 < 10; ++k2) w = w + hv[k2] * z[k2];
      w = w * taui;
      z[i + 1] = z[i + 1] - w;
#pragma unroll
      for (int k2 = i + 2; k2 < 10; ++k2) z[k2] = z[k2] - hv[k2] * w;
    }
  }

  // ---- transpose Z (lane r gets row r) ----
  float zrow[10];
#pragma unroll
  for (int rr2 = 0; rr2 < 10; ++rr2) {
#pragma unroll
    for (int c = 0; c < 10; ++c) {
      float t = __shfl(z[rr2], c, 64);
      if (lane == rr2) zrow[c] = t;
    }
  }

  // ---- fp32 MLP, numpy op order; lane i computes output row i ----
  if (lane < 10) {
    float o = 0.0f;
#pragma unroll
    for (int j = 0; j < 16; ++j) {
      float acc = 0.0f;
#pragma unroll
      for (int k = 0; k < 10; ++k) acc = acc + zrow[k] * W1[j * 10 + k];
      acc = acc + b1[j];
      float h = fmaxf(acc, 0.0f);
      o = o + h * W2[j];
    }
    o = o + b2[0];
    float sig = 1.0f / (1.0f + expf(-o));
    out[lane] = 0.5f * (sig + 1.0f);
  }
}

// ---------------------------------------------------------------------------
extern "C" void kernel_launch(void* const* d_in, const int* in_sizes, int n_in,
                              void* d_out, int out_size, void* d_ws,
                              size_t ws_size, hipStream_t stream) {
  const float* x = (const float*)d_in[0];
  const float* W1 = (const float*)d_in[1];
  const float* b1 = (const float*)d_in[2];
  const float* W2 = (const float*)d_in[3];
  const float* b2 = (const float*)d_in[4];
  float* out = (float*)d_out;

  int nrows = in_sizes[0] / 10;  // 4,000,000

  int kc = KC_DEFAULT;
  for (;;) {
    long nchunks = ((long)nrows + kc - 1) / kc;
    long prow = (nchunks + 63) & ~63L;
    size_t need = (size_t)NACC * prow * sizeof(float) + 256;
    if (need <= ws_size || kc > nrows) break;
    kc *= 2;
  }
  int nchunks = (int)(((long)nrows + kc - 1) / kc);
  int prow = (int)(((long)nchunks + 63) & ~63L);

  float* partial = (float*)d_ws;
  float* G = partial + (size_t)NACC * prow;

  int grid = (nchunks + 63) / 64;
  gram32_kernel<<<grid, 64, 0, stream>>>(x, partial, nrows, kc, nchunks,
                                         prow);
  fold32_kernel<<<NACC, 256, 0, stream>>>(partial, G, nchunks, prow);
  solve_kernel<<<1, 64, 0, stream>>>(G, W1, b1, W2, b2, out);
}

// Round 6
// 180.944 us; speedup vs baseline: 6.7557x; 1.1108x over previous
//
#include <hip/hip_runtime.h>
#include <math.h>

// Bit-exact emulation of the numpy-fp32 reference pipeline:
//   OpenBLAS sgemm fp32 Gram (KC=384 chunked, sequential per-accumulator k
//   order, sequential chunk fold) -> ssyevd fp32 replica -> fp32 MLP.
// Rounds 3/4/5 passed with absmax 0.0 — every fp32 operation ORDER is
// frozen. Round 6: solver state in NAMED SCALARS (ternary-select access,
// never conditional stores -> no LDS demotion; round 5 had d/e demoted to
// 5120B LDS) and Z row-per-lane during SSTEQR (rotations = local FMAs,
// zero shuffles in the hot loop).
#pragma clang fp contract(off)

#define NACC 55         // 10*11/2 packed lower-triangle entries (i, j<=i)
#define KC_DEFAULT 384  // OpenBLAS SGEMM_DEFAULT_Q
#define FOLD_LDS 12288  // 48 KB LDS staging capacity (floats)

// ---------------------------------------------------------------------------
// Gram helpers (unchanged, bit-exact-validated)
// ---------------------------------------------------------------------------
__device__ __forceinline__ void group_load(const float4* __restrict__ xv,
                                           long g, float4* buf) {
#pragma unroll
  for (int t = 0; t < 20; ++t) buf[t] = xv[g * 20 + t];
}

__device__ __forceinline__ void pair_fma_one(const float4 q0, const float4 q1,
                                             const float4 q2, const float4 q3,
                                             const float4 q4, float* acc) {
  float a[10] = {q0.x, q0.y, q0.z, q0.w, q1.x, q1.y, q1.z, q1.w, q2.x, q2.y};
  float b[10] = {q2.z, q2.w, q3.x, q3.y, q3.z, q3.w, q4.x, q4.y, q4.z, q4.w};
  int e = 0;
#pragma unroll
  for (int i = 0; i < 10; ++i)
#pragma unroll
    for (int j = 0; j <= i; ++j) {
      acc[e] = __builtin_fmaf(a[i], a[j], acc[e]);
      acc[e] = __builtin_fmaf(b[i], b[j], acc[e]);
      ++e;
    }
}

__device__ __forceinline__ void group_fma(const float4* buf, float* acc) {
#pragma unroll
  for (int pp = 0; pp < 4; ++pp)
    pair_fma_one(buf[pp * 5 + 0], buf[pp * 5 + 1], buf[pp * 5 + 2],
                 buf[pp * 5 + 3], buf[pp * 5 + 4], acc);
}

__global__ __launch_bounds__(64, 1) void gram32_kernel(
    const float* __restrict__ x, float* __restrict__ partial,
    int nrows, int kc, int nchunks, int prow) {
  int c = blockIdx.x * 64 + threadIdx.x;
  if (c >= nchunks) return;
  long k0 = (long)c * kc;
  long rem = (long)nrows - k0;
  int klen = rem < kc ? (int)rem : kc;

  float acc[NACC];
#pragma unroll
  for (int e = 0; e < NACC; ++e) acc[e] = 0.0f;

  const float4* __restrict__ xv = (const float4*)(x + k0 * 10);
  int npair = klen >> 1;
  int ngrp = npair >> 2;

  float4 bufA[20], bufB[20];

  int g = 0;
  if (ngrp > 0) group_load(xv, 0, bufA);
  while (g < ngrp) {
    if (g + 1 < ngrp) group_load(xv, g + 1, bufB);
    group_fma(bufA, acc);
    ++g;
    if (g >= ngrp) break;
    if (g + 1 < ngrp) group_load(xv, g + 1, bufA);
    group_fma(bufB, acc);
    ++g;
  }
  for (int p = ngrp * 4; p < npair; ++p) {
    float4 v0 = xv[(long)p * 5 + 0];
    float4 v1 = xv[(long)p * 5 + 1];
    float4 v2 = xv[(long)p * 5 + 2];
    float4 v3 = xv[(long)p * 5 + 3];
    float4 v4 = xv[(long)p * 5 + 4];
    pair_fma_one(v0, v1, v2, v3, v4, acc);
  }
  if (klen & 1) {
    const float* row = x + (k0 + klen - 1) * 10;
    float a[10];
#pragma unroll
    for (int i = 0; i < 10; ++i) a[i] = row[i];
    int e = 0;
#pragma unroll
    for (int i = 0; i < 10; ++i)
#pragma unroll
      for (int j = 0; j <= i; ++j) {
        acc[e] = __builtin_fmaf(a[i], a[j], acc[e]);
        ++e;
      }
  }
#pragma unroll
  for (int e = 0; e < NACC; ++e)
    partial[(long)e * prow + c] = acc[e];
}

// ---------------------------------------------------------------------------
// Kernel B: sequential fold (unchanged)
// ---------------------------------------------------------------------------
__global__ __launch_bounds__(256) void fold32_kernel(
    const float* __restrict__ partial, float* __restrict__ G, int nchunks,
    int prow) {
  __shared__ float buf[FOLD_LDS];
  int e = blockIdx.x;
  const float* p = partial + (long)e * prow;

  if (nchunks <= FOLD_LDS) {
    int n4 = nchunks >> 2;
    const float4* p4 = (const float4*)p;
    float4* b4 = (float4*)buf;
    for (int i = threadIdx.x; i < n4; i += 256) b4[i] = p4[i];
    for (int i = (n4 << 2) + threadIdx.x; i < nchunks; i += 256)
      buf[i] = p[i];
    __syncthreads();
    if (threadIdx.x == 0) {
      float s = buf[0];
      int c = 1;
      for (; c + 16 <= nchunks; c += 16) {
        float v[16];
#pragma unroll
        for (int t = 0; t < 16; ++t) v[t] = buf[c + t];
#pragma unroll
        for (int t = 0; t < 16; ++t) s = s + v[t];
      }
      for (; c < nchunks; ++c) s = s + buf[c];
      G[e] = s;
    }
  } else {
    if (threadIdx.x == 0) {
      float s = p[0];
      for (int c = 1; c < nchunks; ++c) s = s + p[c];
      G[e] = s;
    }
  }
}

// ---------------------------------------------------------------------------
// Solver scalar helpers
// ---------------------------------------------------------------------------
__device__ __forceinline__ float s_sign(float a, float b) {
  return copysignf(fabsf(a), b);
}
__device__ __forceinline__ float slapy2(float x, float y) {
  float xa = fabsf(x), ya = fabsf(y);
  float w = fmaxf(xa, ya), z = fminf(xa, ya);
  if (z == 0.0f) return w;
  float t = z / w;
  return w * sqrtf(1.0f + t * t);
}
__device__ __forceinline__ void slartg(float f, float g, float* c, float* s,
                                       float* r) {
  if (g == 0.0f) {
    *c = 1.0f; *s = 0.0f; *r = f;
  } else if (f == 0.0f) {
    *c = 0.0f; *s = s_sign(1.0f, g); *r = fabsf(g);
  } else {
    float d = sqrtf(f * f + g * g);
    *c = fabsf(f) / d;
    *r = s_sign(d, f);
    *s = g / (*r);
  }
}
__device__ void slaev2(float a, float b, float c, float* rt1, float* rt2,
                       float* cs1, float* sn1) {
  float sm = a + c, df = a - c;
  float adf = fabsf(df);
  float tb = b + b;
  float ab = fabsf(tb);
  float acmx, acmn;
  if (fabsf(a) > fabsf(c)) { acmx = a; acmn = c; } else { acmx = c; acmn = a; }
  float rt;
  if (adf > ab) { float t = ab / adf; rt = adf * sqrtf(1.0f + t * t); }
  else if (adf < ab) { float t = adf / ab; rt = ab * sqrtf(1.0f + t * t); }
  else rt = ab * sqrtf(2.0f);
  int sgn1;
  if (sm < 0.0f) {
    *rt1 = 0.5f * (sm - rt); sgn1 = -1;
    *rt2 = (acmx / *rt1) * acmn - (b / *rt1) * b;
  } else if (sm > 0.0f) {
    *rt1 = 0.5f * (sm + rt); sgn1 = 1;
    *rt2 = (acmx / *rt1) * acmn - (b / *rt1) * b;
  } else {
    *rt1 = 0.5f * rt; *rt2 = -0.5f * rt; sgn1 = 1;
  }
  int sgn2;
  float cs;
  if (df >= 0.0f) { cs = df + rt; sgn2 = 1; } else { cs = df - rt; sgn2 = -1; }
  float acs = fabsf(cs);
  if (acs > ab) {
    float ct = -tb / cs;
    *sn1 = 1.0f / sqrtf(1.0f + ct * ct);
    *cs1 = ct * (*sn1);
  } else {
    if (ab == 0.0f) { *cs1 = 1.0f; *sn1 = 0.0f; }
    else {
      float tn = -cs / tb;
      *cs1 = 1.0f / sqrtf(1.0f + tn * tn);
      *sn1 = tn * (*cs1);
    }
  }
  if (sgn1 == sgn2) { float tn = *cs1; *cs1 = -(*sn1); *sn1 = tn; }
}

// Named-scalar select-access macros. Pure cndmask chains; static (post-
// unroll) indices constant-fold to direct register names. NEVER a
// conditional store -> nothing can be demoted to scratch/LDS.
#define GETD(i) ((i)==0?d0:(i)==1?d1:(i)==2?d2:(i)==3?d3:(i)==4?d4:(i)==5?d5:(i)==6?d6:(i)==7?d7:(i)==8?d8:d9)
#define PUTD(i,v) do{int _i=(i);float _x=(v);d0=(_i==0)?_x:d0;d1=(_i==1)?_x:d1;d2=(_i==2)?_x:d2;d3=(_i==3)?_x:d3;d4=(_i==4)?_x:d4;d5=(_i==5)?_x:d5;d6=(_i==6)?_x:d6;d7=(_i==7)?_x:d7;d8=(_i==8)?_x:d8;d9=(_i==9)?_x:d9;}while(0)
#define GETE(i) ((i)==0?e0:(i)==1?e1:(i)==2?e2:(i)==3?e3:(i)==4?e4:(i)==5?e5:(i)==6?e6:(i)==7?e7:e8)
#define PUTE(i,v) do{int _i=(i);float _x=(v);e0=(_i==0)?_x:e0;e1=(_i==1)?_x:e1;e2=(_i==2)?_x:e2;e3=(_i==3)?_x:e3;e4=(_i==4)?_x:e4;e5=(_i==5)?_x:e5;e6=(_i==6)?_x:e6;e7=(_i==7)?_x:e7;e8=(_i==8)?_x:e8;}while(0)
#define GETWC(i) ((i)==0?wc0:(i)==1?wc1:(i)==2?wc2:(i)==3?wc3:(i)==4?wc4:(i)==5?wc5:(i)==6?wc6:(i)==7?wc7:wc8)
#define PUTWC(i,v) do{int _i=(i);float _x=(v);wc0=(_i==0)?_x:wc0;wc1=(_i==1)?_x:wc1;wc2=(_i==2)?_x:wc2;wc3=(_i==3)?_x:wc3;wc4=(_i==4)?_x:wc4;wc5=(_i==5)?_x:wc5;wc6=(_i==6)?_x:wc6;wc7=(_i==7)?_x:wc7;wc8=(_i==8)?_x:wc8;}while(0)
#define GETWS(i) ((i)==0?ws0:(i)==1?ws1:(i)==2?ws2:(i)==3?ws3:(i)==4?ws4:(i)==5?ws5:(i)==6?ws6:(i)==7?ws7:ws8)
#define PUTWS(i,v) do{int _i=(i);float _x=(v);ws0=(_i==0)?_x:ws0;ws1=(_i==1)?_x:ws1;ws2=(_i==2)?_x:ws2;ws3=(_i==3)?_x:ws3;ws4=(_i==4)?_x:ws4;ws5=(_i==5)?_x:ws5;ws6=(_i==6)?_x:ws6;ws7=(_i==7)?_x:ws7;ws8=(_i==8)?_x:ws8;}while(0)
#define GETZ(i) ((i)==0?z0:(i)==1?z1:(i)==2?z2:(i)==3?z3:(i)==4?z4:(i)==5?z5:(i)==6?z6:(i)==7?z7:(i)==8?z8:z9)
#define PUTZ(i,v) do{int _i=(i);float _x=(v);z0=(_i==0)?_x:z0;z1=(_i==1)?_x:z1;z2=(_i==2)?_x:z2;z3=(_i==3)?_x:z3;z4=(_i==4)?_x:z4;z5=(_i==5)?_x:z5;z6=(_i==6)?_x:z6;z7=(_i==7)?_x:z7;z8=(_i==8)?_x:z8;z9=(_i==9)?_x:z9;}while(0)

// ---------------------------------------------------------------------------
// Kernel C: ssyevd fp32 replica + fp32 MLP. One wave. d/e/wc/ws: named
// scalars (redundant per lane, wave-uniform). A: row-per-lane. Z during
// SSTEQR: ROW-per-lane (lane r = row r) so column rotations are lane-local
// register FMAs. SORM2R: column-per-lane (preserves sequential k2 sum).
// ---------------------------------------------------------------------------
__global__ __launch_bounds__(64) void solve_kernel(
    const float* __restrict__ Gp, const float* __restrict__ W1,
    const float* __restrict__ b1, const float* __restrict__ W2,
    const float* __restrict__ b2, float* __restrict__ out) {
  const int lane = threadIdx.x;
  const int myrow = lane < 10 ? lane : 9;

  float row[10];  // static indices only
#pragma unroll
  for (int c = 0; c < 10; ++c) {
    int rr = myrow >= c ? myrow : c;
    int cc = myrow >= c ? c : myrow;
    row[c] = Gp[rr * (rr + 1) / 2 + cc];
  }

  float d0, d1, d2, d3, d4, d5, d6, d7, d8, d9;
  float e0, e1, e2, e3, e4, e5, e6, e7, e8;
  float tau[9];  // static indices only

  // ---- SSYTD2 (UPLO='L'), row-per-lane A (validated in round 5) ----
#pragma unroll
  for (int i = 0; i < 9; ++i) {
    float v[10];
    {
      float myci = row[i];
#pragma unroll
      for (int k = 0; k < 10; ++k) v[k] = __shfl(myci, k, 64);
    }
    float alpha = v[i + 1];
    float xn2 = 0.0f;
#pragma unroll
    for (int k = i + 2; k < 10; ++k) xn2 = xn2 + v[k] * v[k];
    float xnorm = sqrtf(xn2);
    float taui;
    if (xnorm == 0.0f) {
      taui = 0.0f;
      PUTE(i, alpha);
    } else {
      float beta = -s_sign(slapy2(alpha, xnorm), alpha);
      taui = (beta - alpha) / beta;
      float sc = 1.0f / (alpha - beta);
#pragma unroll
      for (int k = i + 2; k < 10; ++k) v[k] = v[k] * sc;
      if (lane >= i + 2 && lane < 10) row[i] = row[i] * sc;
      if (lane == i) {
#pragma unroll
        for (int c = i + 2; c < 10; ++c) row[c] = row[c] * sc;
      }
      if (lane == i + 1) row[i] = beta;
      if (lane == i) row[i + 1] = beta;
      PUTE(i, beta);
    }
    if (taui != 0.0f) {
      v[i + 1] = 1.0f;
      float vme = (lane == i + 1)
                      ? 1.0f
                      : ((lane >= i + 2 && lane < 10) ? row[i] : 0.0f);
      float s = 0.0f;
#pragma unroll
      for (int c2 = i + 1; c2 < 10; ++c2) s = s + row[c2] * v[c2];
      float pvr = taui * s;
      float pva[10];
#pragma unroll
      for (int k = 0; k < 10; ++k) pva[k] = __shfl(pvr, k, 64);
      float dot = 0.0f;
#pragma unroll
      for (int k = i + 1; k < 10; ++k) dot = dot + pva[k] * v[k];
      float alpha2 = -0.5f * taui * dot;
      pvr = pvr + alpha2 * vme;
#pragma unroll
      for (int k = 0; k < 10; ++k) pva[k] = pva[k] + alpha2 * v[k];
      if (lane >= i + 1 && lane < 10) {
#pragma unroll
        for (int c2 = i + 1; c2 < 10; ++c2)
          row[c2] = row[c2] - (vme * pva[c2] + pvr * v[c2]);
      }
    }
    tau[i] = taui;
    PUTD(i, __shfl(row[i], i, 64));
  }
  PUTD(9, __shfl(row[9], 9, 64));

  // ---- SSTEQR('I'), Z row-per-lane: lane r holds Z[r][0..9] ----
  float z0, z1, z2, z3, z4, z5, z6, z7, z8, z9;
  z0 = (lane == 0) ? 1.0f : 0.0f;
  z1 = (lane == 1) ? 1.0f : 0.0f;
  z2 = (lane == 2) ? 1.0f : 0.0f;
  z3 = (lane == 3) ? 1.0f : 0.0f;
  z4 = (lane == 4) ? 1.0f : 0.0f;
  z5 = (lane == 5) ? 1.0f : 0.0f;
  z6 = (lane == 6) ? 1.0f : 0.0f;
  z7 = (lane == 7) ? 1.0f : 0.0f;
  z8 = (lane == 8) ? 1.0f : 0.0f;
  z9 = (lane == 9) ? 1.0f : 0.0f;

  float wc0, wc1, wc2, wc3, wc4, wc5, wc6, wc7, wc8;
  float ws0, ws1, ws2, ws3, ws4, ws5, ws6, ws7, ws8;
  wc0 = wc1 = wc2 = wc3 = wc4 = wc5 = wc6 = wc7 = wc8 = 0.0f;
  ws0 = ws1 = ws2 = ws3 = ws4 = ws5 = ws6 = ws7 = ws8 = 0.0f;

  const float eps = 5.9604644775390625e-08f;
  const float eps2 = 3.5527136788005009e-15f;
  const float safmin = 1.1754943508222875e-38f;
  const int nmaxit = 300;
  int jtot = 0;
  int l1 = 0;

  while (l1 < 10) {
    if (l1 > 0) PUTE(l1 - 1, 0.0f);
    int m = 9;
    {
      bool fnd = false;
#pragma unroll
      for (int mm = 0; mm < 9; ++mm) {
        if (!fnd && mm >= l1) {
          float tst = fabsf(GETE(mm));
          if (tst == 0.0f) {
            m = mm; fnd = true;
          } else if (tst <=
                     (sqrtf(fabsf(GETD(mm))) * sqrtf(fabsf(GETD(mm + 1)))) *
                         eps) {
            PUTE(mm, 0.0f); m = mm; fnd = true;
          }
        }
      }
    }
    int l = l1, lsv = l, lend = m, lendsv = lend;
    l1 = m + 1;
    if (lend == l) continue;
    float anorm = 0.0f;
#pragma unroll
    for (int k = 0; k < 10; ++k)
      if (k >= l && k <= lend) anorm = fmaxf(anorm, fabsf(GETD(k)));
#pragma unroll
    for (int k = 0; k < 9; ++k)
      if (k >= l && k < lend) anorm = fmaxf(anorm, fabsf(GETE(k)));
    if (anorm == 0.0f) continue;
    if (fabsf(GETD(lend)) < fabsf(GETD(l))) { lend = lsv; l = lendsv; }

    if (lend > l) {
      // --- QL ---
      for (;;) {
        int m2 = lend;
        if (l != lend) {
          bool fnd = false;
#pragma unroll
          for (int mm = 0; mm < 9; ++mm) {
            if (!fnd && mm >= l && mm <= lend - 1) {
              float tst = GETE(mm) * GETE(mm);
              if (tst <=
                  (eps2 * fabsf(GETD(mm))) * fabsf(GETD(mm + 1)) + safmin) {
                m2 = mm; fnd = true;
              }
            }
          }
        }
        if (m2 < lend) PUTE(m2, 0.0f);
        float p = GETD(l);
        if (m2 == l) {
          ++l;
          if (l <= lend) continue;
          break;
        }
        if (m2 == l + 1) {
          float rt1, rt2, cc2, ss2;
          slaev2(GETD(l), GETE(l), GETD(l + 1), &rt1, &rt2, &cc2, &ss2);
          {
            float zl = GETZ(l), zl1 = GETZ(l + 1);
            float t = zl1;
            float nl1 = cc2 * t - ss2 * zl;
            float nl = ss2 * t + cc2 * zl;
            PUTZ(l + 1, nl1);
            PUTZ(l, nl);
          }
          PUTD(l, rt1);
          PUTD(l + 1, rt2);
          PUTE(l, 0.0f);
          l += 2;
          if (l <= lend) continue;
          break;
        }
        if (jtot == nmaxit) break;
        ++jtot;
        float g = (GETD(l + 1) - p) / (2.0f * GETE(l));
        float r2 = slapy2(g, 1.0f);
        g = GETD(m2) - p + (GETE(l) / (g + s_sign(r2, g)));
        float ss = 1.0f, cc = 1.0f;
        p = 0.0f;
#pragma unroll
        for (int i2 = 8; i2 >= 0; --i2) {
          if (i2 >= l && i2 <= m2 - 1) {
            float f = ss * GETE(i2);
            float bb = cc * GETE(i2);
            slartg(g, f, &cc, &ss, &r2);
            if (i2 != m2 - 1) PUTE(i2 + 1, r2);
            g = GETD(i2 + 1) - p;
            r2 = (GETD(i2) - g) * ss + 2.0f * cc * bb;
            p = ss * r2;
            PUTD(i2 + 1, g + p);
            g = cc * r2 - bb;
            PUTWC(i2, cc);
            PUTWS(i2, -ss);
          }
        }
#pragma unroll
        for (int j = 8; j >= 0; --j) {  // SLASR 'R','V','B' — lane-local
          if (j >= l && j <= m2 - 1) {
            float cj = GETWC(j), sj = GETWS(j);
            float t = GETZ(j + 1);
            float zj = GETZ(j);
            PUTZ(j + 1, cj * t - sj * zj);
            PUTZ(j, sj * t + cj * zj);
          }
        }
        PUTD(l, GETD(l) - p);
        PUTE(l, g);
      }
    } else {
      // --- QR ---
      for (;;) {
        int m2 = lend;
        if (l != lend) {
          bool fnd = false;
#pragma unroll
          for (int mm = 9; mm >= 1; --mm) {
            if (!fnd && mm <= l && mm >= lend + 1) {
              float tst = GETE(mm - 1) * GETE(mm - 1);
              if (tst <=
                  (eps2 * fabsf(GETD(mm))) * fabsf(GETD(mm - 1)) + safmin) {
                m2 = mm; fnd = true;
              }
            }
          }
        }
        if (m2 > lend) PUTE(m2 - 1, 0.0f);
        float p = GETD(l);
        if (m2 == l) {
          --l;
          if (l >= lend) continue;
          break;
        }
        if (m2 == l - 1) {
          float rt1, rt2, cc2, ss2;
          slaev2(GETD(l - 1), GETE(l - 1), GETD(l), &rt1, &rt2, &cc2, &ss2);
          {
            float zl = GETZ(l), zlm = GETZ(l - 1);
            float t = zl;
            float nl = cc2 * t - ss2 * zlm;
            float nlm = ss2 * t + cc2 * zlm;
            PUTZ(l, nl);
            PUTZ(l - 1, nlm);
          }
          PUTD(l - 1, rt1);
          PUTD(l, rt2);
          PUTE(l - 1, 0.0f);
          l -= 2;
          if (l >= lend) continue;
          break;
        }
        if (jtot == nmaxit) break;
        ++jtot;
        float g = (GETD(l - 1) - p) / (2.0f * GETE(l - 1));
        float r2 = slapy2(g, 1.0f);
        g = GETD(m2) - p + (GETE(l - 1) / (g + s_sign(r2, g)));
        float ss = 1.0f, cc = 1.0f;
        p = 0.0f;
#pragma unroll
        for (int i2 = 0; i2 <= 8; ++i2) {
          if (i2 >= m2 && i2 <= l - 1) {
            float f = ss * GETE(i2);
            float bb = cc * GETE(i2);
            slartg(g, f, &cc, &ss, &r2);
            if (i2 != m2) PUTE(i2 - 1, r2);
            g = GETD(i2) - p;
            r2 = (GETD(i2 + 1) - g) * ss + 2.0f * cc * bb;
            p = ss * r2;
            PUTD(i2, g + p);
            g = cc * r2 - bb;
            PUTWC(i2, cc);
            PUTWS(i2, ss);
          }
        }
#pragma unroll
        for (int j = 0; j <= 8; ++j) {  // SLASR 'R','V','F' — lane-local
          if (j >= m2 && j <= l - 1) {
            float cj = GETWC(j), sj = GETWS(j);
            float t = GETZ(j + 1);
            float zj = GETZ(j);
            PUTZ(j + 1, cj * t - sj * zj);
            PUTZ(j, sj * t + cj * zj);
          }
        }
        PUTD(l, GETD(l) - p);
        PUTE(l - 1, g);
      }
    }
  }

  // ---- ascending selection sort (d uniform; Z column swap lane-local) ----
#pragma unroll
  for (int ii = 1; ii < 10; ++ii) {
    const int i2 = ii - 1;
    int k2 = i2;
    float pmin = GETD(i2);
#pragma unroll
    for (int j = ii; j < 10; ++j) {
      float dj = GETD(j);
      if (dj < pmin) { k2 = j; pmin = dj; }
    }
    if (k2 != i2) {
      PUTD(k2, GETD(i2));
      PUTD(i2, pmin);
      float ti = GETZ(i2);
      float tk = GETZ(k2);
      PUTZ(i2, tk);
      PUTZ(k2, ti);
    }
  }

  // ---- transpose Z: row-per-lane -> column-per-lane (lane j = col j) ----
  float zc[10];  // static indices only
#pragma unroll
  for (int r = 0; r < 10; ++r) zc[r] = 0.0f;
  {
    float zreg[10] = {z0, z1, z2, z3, z4, z5, z6, z7, z8, z9};
#pragma unroll
    for (int r = 0; r < 10; ++r) {
#pragma unroll
      for (int c = 0; c < 10; ++c) {
        float t = __shfl(zreg[c], r, 64);  // Z[r][c]
        zc[r] = (lane == c) ? t : zc[r];
      }
    }
  }

  // ---- SORM2R: V = H(0)...H(7) * Z ; lane j owns column j ----
#pragma unroll
  for (int i = 8; i >= 0; --i) {
    float taui = tau[i];
    if (taui != 0.0f) {
      float hv[10];
      {
        float myci = row[i];
#pragma unroll
        for (int k = 0; k < 10; ++k) hv[k] = __shfl(myci, k, 64);
      }
      float w = zc[i + 1];
#pragma unroll
      for (int k2 = i + 2; k2 < 10; ++k2) w = w + hv[k2] * zc[k2];
      w = w * taui;
      zc[i + 1] = zc[i + 1] - w;
#pragma unroll
      for (int k2 = i + 2; k2 < 10; ++k2) zc[k2] = zc[k2] - hv[k2] * w;
    }
  }

  // ---- transpose back: column-per-lane -> row-per-lane ----
  float zrow[10];
#pragma unroll
  for (int c = 0; c < 10; ++c) zrow[c] = 0.0f;
#pragma unroll
  for (int r = 0; r < 10; ++r) {
#pragma unroll
    for (int c = 0; c < 10; ++c) {
      float t = __shfl(zc[r], c, 64);  // Z[r][c] from lane c
      zrow[c] = (lane == r) ? t : zrow[c];
    }
  }

  // ---- fp32 MLP, numpy op order; lane i computes output row i ----
  if (lane < 10) {
    float o = 0.0f;
#pragma unroll
    for (int j = 0; j < 16; ++j) {
      float acc = 0.0f;
#pragma unroll
      for (int k = 0; k < 10; ++k) acc = acc + zrow[k] * W1[j * 10 + k];
      acc = acc + b1[j];
      float h = fmaxf(acc, 0.0f);
      o = o + h * W2[j];
    }
    o = o + b2[0];
    float sig = 1.0f / (1.0f + expf(-o));
    out[lane] = 0.5f * (sig + 1.0f);
  }
}

// ---------------------------------------------------------------------------
extern "C" void kernel_launch(void* const* d_in, const int* in_sizes, int n_in,
                              void* d_out, int out_size, void* d_ws,
                              size_t ws_size, hipStream_t stream) {
  const float* x = (const float*)d_in[0];
  const float* W1 = (const float*)d_in[1];
  const float* b1 = (const float*)d_in[2];
  const float* W2 = (const float*)d_in[3];
  const float* b2 = (const float*)d_in[4];
  float* out = (float*)d_out;

  int nrows = in_sizes[0] / 10;  // 4,000,000

  int kc = KC_DEFAULT;
  for (;;) {
    long nchunks = ((long)nrows + kc - 1) / kc;
    long prow = (nchunks + 63) & ~63L;
    size_t need = (size_t)NACC * prow * sizeof(float) + 256;
    if (need <= ws_size || kc > nrows) break;
    kc *= 2;
  }
  int nchunks = (int)(((long)nrows + kc - 1) / kc);
  int prow = (int)(((long)nchunks + 63) & ~63L);

  float* partial = (float*)d_ws;
  float* G = partial + (size_t)NACC * prow;

  int grid = (nchunks + 63) / 64;
  gram32_kernel<<<grid, 64, 0, stream>>>(x, partial, nrows, kc, nchunks,
                                         prow);
  fold32_kernel<<<NACC, 256, 0, stream>>>(partial, G, nchunks, prow);
  solve_kernel<<<1, 64, 0, stream>>>(G, W1, b1, W2, b2, out);
}